// Round 4
// baseline (407.799 us; speedup 1.0000x reference)
//
#include <hip/hip_runtime.h>
#include <math.h>

#define HIDDEN 1024
#define VOCAB  50257
#define MAXLEN 64
#define GRID   1024
#define NW     (GRID * 4)                       // 4096 waves
#define TOTAL4 (VOCAB * 256)                    // out_W float4 count = 12,865,792
#define NWARM  491                              // blocks 533..1023

__device__ __forceinline__ float wave_reduce_sum(float v) {
    #pragma unroll
    for (int off = 32; off > 0; off >>= 1)
        v += __shfl_down(v, off, 64);
    return v;
}

// counters: cnt[0]=scores(64) cnt[1]=softmax(1) cnt[2]=ctx(4) cnt[3]=combine(1024) cnt[4]=gru(1024)
__device__ __forceinline__ void block_wait(int* c, int target) {
    if (threadIdx.x == 0) {
        int guard = 0;
        while (__hip_atomic_load(c, __ATOMIC_ACQUIRE, __HIP_MEMORY_SCOPE_AGENT) < target) {
            __builtin_amdgcn_s_sleep(1);
            if (++guard > (1 << 24)) break;   // safety bail: wrong-answer beats hang
        }
    }
    __syncthreads();
}

__global__ __launch_bounds__(256, 4) void k_fused(
    const int* __restrict__ token,
    const float* __restrict__ emb,
    const float* __restrict__ hidden,
    const float* __restrict__ enc,
    const float* __restrict__ attn_W,
    const float* __restrict__ attn_b,
    const float* __restrict__ comb_W,
    const float* __restrict__ comb_b,
    const float* __restrict__ W_ih,
    const float* __restrict__ W_hh,
    const float* __restrict__ b_ih,
    const float* __restrict__ b_hh,
    const float* __restrict__ out_W,
    const float* __restrict__ out_b,
    int* __restrict__ cnt,
    float* __restrict__ s_sc,    // [64]
    float* __restrict__ s_w,     // [64]
    float* __restrict__ s_ctx,   // [1024]
    float* __restrict__ s_x,     // [1024]
    float* __restrict__ s_h,     // [1024]
    float* __restrict__ out_logits,
    float* __restrict__ out_h,
    float* __restrict__ out_attn)
{
    __shared__ float wsm[MAXLEN];
    __shared__ float4 hn4[HIDDEN / 4];

    const int t = threadIdx.x;
    const int wid = t >> 6, lane = t & 63;
    const int b = blockIdx.x;

    if (b < 16) {
        // ---- scores: wave per row m = b*4+wid ----
        const int m = b * 4 + wid;
        const float4* e4 = (const float4*)(emb + (size_t)token[0] * HIDDEN);
        const float4* h4 = (const float4*)hidden;
        const float4* Wr = (const float4*)(attn_W + (size_t)m * 2 * HIDDEN);
        float acc = 0.f;
        #pragma unroll
        for (int it = 0; it < 8; ++it) {
            int i = lane + it * 64;                       // 0..511 float4s
            float4 a = Wr[i];
            float4 c = (i < 256) ? e4[i] : h4[i - 256];
            acc += a.x * c.x + a.y * c.y + a.z * c.z + a.w * c.w;
        }
        acc = wave_reduce_sum(acc);
        if (lane == 0) {
            s_sc[m] = acc + attn_b[m];
            __threadfence();
            atomicAdd(&cnt[0], 1);
        }
    } else if (b == 16) {
        // ---- softmax over 64 scores (wave 0) ----
        block_wait(&cnt[0], 64);
        if (wid == 0) {
            float s = s_sc[lane];
            float mx = s;
            #pragma unroll
            for (int off = 32; off > 0; off >>= 1) mx = fmaxf(mx, __shfl_xor(mx, off, 64));
            float e = expf(s - mx);
            float sum = e;
            #pragma unroll
            for (int off = 32; off > 0; off >>= 1) sum += __shfl_xor(sum, off, 64);
            float wv = e / sum;
            s_w[lane] = wv;
            out_attn[lane] = wv;
            __threadfence();
            if (lane == 0) atomicAdd(&cnt[1], 1);
        }
    } else if (b < 21) {
        // ---- context: 4 blocks x 256 cols ----
        block_wait(&cnt[1], 1);
        if (t < MAXLEN) wsm[t] = s_w[t];
        __syncthreads();
        const int h = (b - 17) * 256 + t;
        float acc = 0.f;
        #pragma unroll 8
        for (int m = 0; m < MAXLEN; ++m)
            acc += wsm[m] * enc[(size_t)m * HIDDEN + h];
        s_ctx[h] = acc;
        __threadfence();
        __syncthreads();
        if (t == 0) atomicAdd(&cnt[2], 1);
    } else if (b < 277) {
        // ---- combine: wave per row j ----
        block_wait(&cnt[2], 4);
        const int j = (b - 21) * 4 + wid;
        const float4* e4 = (const float4*)(emb + (size_t)token[0] * HIDDEN);
        const float4* c4 = (const float4*)s_ctx;
        const float4* Wr = (const float4*)(comb_W + (size_t)j * 2 * HIDDEN);
        float acc = 0.f;
        #pragma unroll
        for (int it = 0; it < 8; ++it) {
            int i = lane + it * 64;
            float4 a = Wr[i];
            float4 c = (i < 256) ? e4[i] : c4[i - 256];
            acc += a.x * c.x + a.y * c.y + a.z * c.z + a.w * c.w;
        }
        acc = wave_reduce_sum(acc);
        if (lane == 0) {
            s_x[j] = fmaxf(acc + comb_b[j], 0.f);
            __threadfence();
            atomicAdd(&cnt[3], 1);
        }
    } else if (b < 533) {
        // ---- GRU: wave per output element j, 6 sequential gate dots ----
        block_wait(&cnt[3], 1024);
        const int j = (b - 277) * 4 + wid;
        float d[6];
        const float* rows[6] = {
            W_ih + (size_t)j * HIDDEN,
            W_ih + (size_t)(j + HIDDEN) * HIDDEN,
            W_ih + (size_t)(j + 2 * HIDDEN) * HIDDEN,
            W_hh + (size_t)j * HIDDEN,
            W_hh + (size_t)(j + HIDDEN) * HIDDEN,
            W_hh + (size_t)(j + 2 * HIDDEN) * HIDDEN };
        const float* vecs[2] = { s_x, hidden };
        #pragma unroll
        for (int q = 0; q < 6; ++q) {
            const float4* W4 = (const float4*)rows[q];
            const float4* v4 = (const float4*)vecs[q / 3];
            float acc = 0.f;
            #pragma unroll
            for (int it = 0; it < 4; ++it) {
                int i = lane + it * 64;
                float4 a = W4[i];
                float4 v = v4[i];
                acc += a.x * v.x + a.y * v.y + a.z * v.z + a.w * v.w;
            }
            d[q] = wave_reduce_sum(acc);
        }
        if (lane == 0) {
            float i_r = d[0] + b_ih[j];
            float i_z = d[1] + b_ih[j + HIDDEN];
            float i_n = d[2] + b_ih[j + 2 * HIDDEN];
            float h_r = d[3] + b_hh[j];
            float h_z = d[4] + b_hh[j + HIDDEN];
            float h_n = d[5] + b_hh[j + 2 * HIDDEN];
            float r = 1.f / (1.f + expf(-(i_r + h_r)));
            float z = 1.f / (1.f + expf(-(i_z + h_z)));
            float n = tanhf(i_n + r * h_n);
            float h0v = hidden[j];
            float hn = (1.f - z) * n + z * h0v;
            s_h[j] = hn;
            out_h[j] = hn;
            __threadfence();
            atomicAdd(&cnt[4], 1);
        }
    } else {
        // ---- idle blocks: warm L3 with out_W until h_new is ready ----
        const float4* w4 = (const float4*)out_W;
        const int wb = b - 533;                       // 0..490
        const int per = (TOTAL4 + NWARM - 1) / NWARM; // 26204 float4s
        const int start = wb * per;
        const int end = (start + per < TOTAL4) ? (start + per) : TOTAL4;
        for (int base = start; base < end; base += 2048) {
            #pragma unroll
            for (int s = 0; s < 8; ++s) {
                int idx = base + s * 256 + t;
                if (idx < end) {
                    float4 v = w4[idx];
                    asm volatile("" :: "v"(v.x), "v"(v.y), "v"(v.z), "v"(v.w));
                }
            }
            if (__hip_atomic_load(&cnt[4], __ATOMIC_RELAXED, __HIP_MEMORY_SCOPE_AGENT) >= 1024)
                break;
        }
    }

    // ---- logits: all 1024 blocks, grid-stride, 2 rows per wave ----
    block_wait(&cnt[4], 1024);
    hn4[t] = ((const float4*)s_h)[t];
    __syncthreads();

    const int g = b * 4 + wid;
    for (int v0 = g * 2; v0 < VOCAB; v0 += NW * 2) {
        const int v1 = v0 + 1;
        const bool has1 = (v1 < VOCAB);
        const float4* W0 = (const float4*)(out_W + (size_t)v0 * HIDDEN);
        const float4* W1 = (const float4*)(out_W + (size_t)v1 * HIDDEN);
        float acc0 = 0.f, acc1 = 0.f;
        #pragma unroll
        for (int i = 0; i < 4; ++i) {
            const int idx = lane + i * 64;
            float4 hv = hn4[idx];
            float4 a0 = W0[idx];
            acc0 += a0.x * hv.x + a0.y * hv.y + a0.z * hv.z + a0.w * hv.w;
            if (has1) {
                float4 a1 = W1[idx];
                acc1 += a1.x * hv.x + a1.y * hv.y + a1.z * hv.z + a1.w * hv.w;
            }
        }
        acc0 = wave_reduce_sum(acc0);
        acc1 = wave_reduce_sum(acc1);
        if (lane == 0) {
            out_logits[v0] = acc0 + out_b[v0];
            if (has1) out_logits[v1] = acc1 + out_b[v1];
        }
    }
}

extern "C" void kernel_launch(void* const* d_in, const int* in_sizes, int n_in,
                              void* d_out, int out_size, void* d_ws, size_t ws_size,
                              hipStream_t stream) {
    const int*   token  = (const int*)d_in[0];
    const float* hidden = (const float*)d_in[1];
    const float* enc    = (const float*)d_in[2];
    const float* emb    = (const float*)d_in[3];
    const float* attn_W = (const float*)d_in[4];
    const float* attn_b = (const float*)d_in[5];
    const float* comb_W = (const float*)d_in[6];
    const float* comb_b = (const float*)d_in[7];
    const float* W_ih   = (const float*)d_in[8];
    const float* W_hh   = (const float*)d_in[9];
    const float* b_ih   = (const float*)d_in[10];
    const float* b_hh   = (const float*)d_in[11];
    const float* out_W  = (const float*)d_in[12];
    const float* out_b  = (const float*)d_in[13];

    float* out = (float*)d_out;
    float* out_logits = out;                       // [50257]
    float* out_h      = out + VOCAB;               // [1024]
    float* out_attn   = out + VOCAB + HIDDEN;      // [64]

    int* cnt = (int*)d_ws;                         // 16 ints (64 B)
    float* wsf = (float*)((char*)d_ws + 64);
    float* s_sc  = wsf;            // 64
    float* s_w   = wsf + 64;       // 64
    float* s_ctx = wsf + 128;      // 1024
    float* s_x   = wsf + 1152;     // 1024
    float* s_h   = wsf + 2176;     // 1024

    hipMemsetAsync(d_ws, 0, 64, stream);
    k_fused<<<GRID, 256, 0, stream>>>(token, emb, hidden, enc, attn_W, attn_b,
                                      comb_W, comb_b, W_ih, W_hh, b_ih, b_hh,
                                      out_W, out_b, cnt, s_sc, s_w, s_ctx, s_x, s_h,
                                      out_logits, out_h, out_attn);
}

// Round 5
// 121.830 us; speedup vs baseline: 3.3473x; 3.3473x over previous
//
#include <hip/hip_runtime.h>
#include <math.h>

#define HIDDEN 1024
#define VOCAB  50257
#define MAXLEN 64
#define GRID   1024
#define NW     (GRID * 4)                       // 4096 waves
#define TOTAL4 (VOCAB * 256)                    // out_W float4 count = 12,865,792
#define NWARM  491                              // blocks 533..1023

__device__ __forceinline__ float wave_reduce_sum(float v) {
    #pragma unroll
    for (int off = 32; off > 0; off >>= 1)
        v += __shfl_down(v, off, 64);
    return v;
}

// Relaxed-poll (no cache invalidate per iteration), then ONE acquire load to
// establish ordering. Round-4 lesson: ACQUIRE in the poll loop emits
// buffer_inv every iteration -> continuous L2 invalidation -> 430 GB/s.
__device__ __forceinline__ void block_wait(int* c, int target) {
    if (threadIdx.x == 0) {
        int guard = 0;
        while (__hip_atomic_load(c, __ATOMIC_RELAXED, __HIP_MEMORY_SCOPE_AGENT) < target) {
            __builtin_amdgcn_s_sleep(1);
            if (++guard > (1 << 24)) break;   // safety bail: wrong-answer beats hang
        }
        (void)__hip_atomic_load(c, __ATOMIC_ACQUIRE, __HIP_MEMORY_SCOPE_AGENT);
    }
    __syncthreads();
}

__device__ __forceinline__ void block_signal(int* c, int amt) {
    // one RELEASE atomic per block (single L2 writeback covers the whole
    // block's prior stores — same CU -> same XCD L2)
    __syncthreads();
    if (threadIdx.x == 0)
        __hip_atomic_fetch_add(c, amt, __ATOMIC_RELEASE, __HIP_MEMORY_SCOPE_AGENT);
}

// counters: cnt[0]=scores(16 blocks) cnt[1]=softmax(1) cnt[2]=ctx(4) cnt[3]=combine(256) cnt[4]=gru(256)
__global__ __launch_bounds__(256, 4) void k_fused(
    const int* __restrict__ token,
    const float* __restrict__ emb,
    const float* __restrict__ hidden,
    const float* __restrict__ enc,
    const float* __restrict__ attn_W,
    const float* __restrict__ attn_b,
    const float* __restrict__ comb_W,
    const float* __restrict__ comb_b,
    const float* __restrict__ W_ih,
    const float* __restrict__ W_hh,
    const float* __restrict__ b_ih,
    const float* __restrict__ b_hh,
    const float* __restrict__ out_W,
    const float* __restrict__ out_b,
    int* __restrict__ cnt,
    float* __restrict__ s_sc,    // [64]
    float* __restrict__ s_w,     // [64]
    float* __restrict__ s_ctx,   // [1024]
    float* __restrict__ s_x,     // [1024]
    float* __restrict__ s_h,     // [1024]
    float* __restrict__ out_logits,
    float* __restrict__ out_h,
    float* __restrict__ out_attn)
{
    __shared__ float wsm[MAXLEN];
    __shared__ float4 hn4[HIDDEN / 4];

    const int t = threadIdx.x;
    const int wid = t >> 6, lane = t & 63;
    const int b = blockIdx.x;

    if (b < 16) {
        // ---- scores: wave per row m = b*4+wid ----
        const int m = b * 4 + wid;
        const float4* e4 = (const float4*)(emb + (size_t)token[0] * HIDDEN);
        const float4* h4 = (const float4*)hidden;
        const float4* Wr = (const float4*)(attn_W + (size_t)m * 2 * HIDDEN);
        float acc = 0.f;
        #pragma unroll
        for (int it = 0; it < 8; ++it) {
            int i = lane + it * 64;                       // 0..511 float4s
            float4 a = Wr[i];
            float4 c = (i < 256) ? e4[i] : h4[i - 256];
            acc += a.x * c.x + a.y * c.y + a.z * c.z + a.w * c.w;
        }
        acc = wave_reduce_sum(acc);
        if (lane == 0) s_sc[m] = acc + attn_b[m];
        block_signal(&cnt[0], 1);
    } else if (b == 16) {
        // ---- softmax over 64 scores (wave 0) ----
        block_wait(&cnt[0], 16);
        if (wid == 0) {
            float s = s_sc[lane];
            float mx = s;
            #pragma unroll
            for (int off = 32; off > 0; off >>= 1) mx = fmaxf(mx, __shfl_xor(mx, off, 64));
            float e = expf(s - mx);
            float sum = e;
            #pragma unroll
            for (int off = 32; off > 0; off >>= 1) sum += __shfl_xor(sum, off, 64);
            float wv = e / sum;
            s_w[lane] = wv;
            out_attn[lane] = wv;
        }
        block_signal(&cnt[1], 1);
    } else if (b < 21) {
        // ---- context: 4 blocks x 256 cols ----
        block_wait(&cnt[1], 1);
        if (t < MAXLEN) wsm[t] = s_w[t];
        __syncthreads();
        const int h = (b - 17) * 256 + t;
        float acc = 0.f;
        #pragma unroll 8
        for (int m = 0; m < MAXLEN; ++m)
            acc += wsm[m] * enc[(size_t)m * HIDDEN + h];
        s_ctx[h] = acc;
        block_signal(&cnt[2], 1);
    } else if (b < 277) {
        // ---- combine: wave per row j ----
        block_wait(&cnt[2], 4);
        const int j = (b - 21) * 4 + wid;
        const float4* e4 = (const float4*)(emb + (size_t)token[0] * HIDDEN);
        const float4* c4 = (const float4*)s_ctx;
        const float4* Wr = (const float4*)(comb_W + (size_t)j * 2 * HIDDEN);
        float acc = 0.f;
        #pragma unroll
        for (int it = 0; it < 8; ++it) {
            int i = lane + it * 64;
            float4 a = Wr[i];
            float4 c = (i < 256) ? e4[i] : c4[i - 256];
            acc += a.x * c.x + a.y * c.y + a.z * c.z + a.w * c.w;
        }
        acc = wave_reduce_sum(acc);
        if (lane == 0) s_x[j] = fmaxf(acc + comb_b[j], 0.f);
        block_signal(&cnt[3], 1);
    } else if (b < 533) {
        // ---- GRU: wave per output element j, 6 sequential gate dots ----
        block_wait(&cnt[3], 256);
        const int j = (b - 277) * 4 + wid;
        float d[6];
        const float* rows[6] = {
            W_ih + (size_t)j * HIDDEN,
            W_ih + (size_t)(j + HIDDEN) * HIDDEN,
            W_ih + (size_t)(j + 2 * HIDDEN) * HIDDEN,
            W_hh + (size_t)j * HIDDEN,
            W_hh + (size_t)(j + HIDDEN) * HIDDEN,
            W_hh + (size_t)(j + 2 * HIDDEN) * HIDDEN };
        const float* vecs[2] = { s_x, hidden };
        #pragma unroll
        for (int q = 0; q < 6; ++q) {
            const float4* W4 = (const float4*)rows[q];
            const float4* v4 = (const float4*)vecs[q / 3];
            float acc = 0.f;
            #pragma unroll
            for (int it = 0; it < 4; ++it) {
                int i = lane + it * 64;
                float4 a = W4[i];
                float4 v = v4[i];
                acc += a.x * v.x + a.y * v.y + a.z * v.z + a.w * v.w;
            }
            d[q] = wave_reduce_sum(acc);
        }
        if (lane == 0) {
            float i_r = d[0] + b_ih[j];
            float i_z = d[1] + b_ih[j + HIDDEN];
            float i_n = d[2] + b_ih[j + 2 * HIDDEN];
            float h_r = d[3] + b_hh[j];
            float h_z = d[4] + b_hh[j + HIDDEN];
            float h_n = d[5] + b_hh[j + 2 * HIDDEN];
            float r = 1.f / (1.f + expf(-(i_r + h_r)));
            float z = 1.f / (1.f + expf(-(i_z + h_z)));
            float n = tanhf(i_n + r * h_n);
            float h0v = hidden[j];
            float hn = (1.f - z) * n + z * h0v;
            s_h[j] = hn;
            out_h[j] = hn;
        }
        block_signal(&cnt[4], 1);
    } else {
        // ---- idle blocks: warm L3 with out_W until h_new is ready ----
        // (L3 is memory-side: survives the agent-scope buffer_inv at the gate)
        const float4* w4 = (const float4*)out_W;
        const int wb = b - 533;                       // 0..490
        const int per = (TOTAL4 + NWARM - 1) / NWARM; // 26204 float4s
        const int start = wb * per;
        const int end = (start + per < TOTAL4) ? (start + per) : TOTAL4;
        for (int base = start; base < end; base += 2048) {
            #pragma unroll
            for (int s = 0; s < 8; ++s) {
                int idx = base + s * 256 + t;
                if (idx < end) {
                    float4 v = w4[idx];
                    asm volatile("" :: "v"(v.x), "v"(v.y), "v"(v.z), "v"(v.w));
                }
            }
            if (__hip_atomic_load(&cnt[4], __ATOMIC_RELAXED, __HIP_MEMORY_SCOPE_AGENT) >= 256)
                break;
        }
    }

    // ---- logits: all 1024 blocks, grid-stride, 2 rows per wave ----
    block_wait(&cnt[4], 256);
    hn4[t] = ((const float4*)s_h)[t];
    __syncthreads();

    const int g = b * 4 + wid;
    for (int v0 = g * 2; v0 < VOCAB; v0 += NW * 2) {
        const int v1 = v0 + 1;
        const bool has1 = (v1 < VOCAB);
        const float4* W0 = (const float4*)(out_W + (size_t)v0 * HIDDEN);
        const float4* W1 = (const float4*)(out_W + (size_t)v1 * HIDDEN);
        float acc0 = 0.f, acc1 = 0.f;
        #pragma unroll
        for (int i = 0; i < 4; ++i) {
            const int idx = lane + i * 64;
            float4 hv = hn4[idx];
            float4 a0 = W0[idx];
            acc0 += a0.x * hv.x + a0.y * hv.y + a0.z * hv.z + a0.w * hv.w;
            if (has1) {
                float4 a1 = W1[idx];
                acc1 += a1.x * hv.x + a1.y * hv.y + a1.z * hv.z + a1.w * hv.w;
            }
        }
        acc0 = wave_reduce_sum(acc0);
        acc1 = wave_reduce_sum(acc1);
        if (lane == 0) {
            out_logits[v0] = acc0 + out_b[v0];
            if (has1) out_logits[v1] = acc1 + out_b[v1];
        }
    }
}

extern "C" void kernel_launch(void* const* d_in, const int* in_sizes, int n_in,
                              void* d_out, int out_size, void* d_ws, size_t ws_size,
                              hipStream_t stream) {
    const int*   token  = (const int*)d_in[0];
    const float* hidden = (const float*)d_in[1];
    const float* enc    = (const float*)d_in[2];
    const float* emb    = (const float*)d_in[3];
    const float* attn_W = (const float*)d_in[4];
    const float* attn_b = (const float*)d_in[5];
    const float* comb_W = (const float*)d_in[6];
    const float* comb_b = (const float*)d_in[7];
    const float* W_ih   = (const float*)d_in[8];
    const float* W_hh   = (const float*)d_in[9];
    const float* b_ih   = (const float*)d_in[10];
    const float* b_hh   = (const float*)d_in[11];
    const float* out_W  = (const float*)d_in[12];
    const float* out_b  = (const float*)d_in[13];

    float* out = (float*)d_out;
    float* out_logits = out;                       // [50257]
    float* out_h      = out + VOCAB;               // [1024]
    float* out_attn   = out + VOCAB + HIDDEN;      // [64]

    int* cnt = (int*)d_ws;                         // 16 ints (64 B)
    float* wsf = (float*)((char*)d_ws + 64);
    float* s_sc  = wsf;            // 64
    float* s_w   = wsf + 64;       // 64
    float* s_ctx = wsf + 128;      // 1024
    float* s_x   = wsf + 1152;     // 1024
    float* s_h   = wsf + 2176;     // 1024

    hipMemsetAsync(d_ws, 0, 64, stream);
    k_fused<<<GRID, 256, 0, stream>>>(token, emb, hidden, enc, attn_W, attn_b,
                                      comb_W, comb_b, W_ih, W_hh, b_ih, b_hh,
                                      out_W, out_b, cnt, s_sc, s_w, s_ctx, s_x, s_h,
                                      out_logits, out_h, out_attn);
}

// Round 6
// 71.126 us; speedup vs baseline: 5.7335x; 1.7129x over previous
//
#include <hip/hip_runtime.h>
#include <math.h>

#define HIDDEN 1024
#define VOCAB  50257
#define MAXLEN 64

__device__ __forceinline__ float wave_reduce_sum(float v) {
    #pragma unroll
    for (int off = 32; off > 0; off >>= 1)
        v += __shfl_down(v, off, 64);
    return v;
}

// Counters live on SEPARATE 128-B lines: cnt + i*32 ints.
// Round-5 lesson: one shared line + tight polls = coherence-point queueing
// (159 us with zero HBM traffic). Damped relaxed poll + separate lines.
__device__ __forceinline__ void block_wait(int* c, int target) {
    if (threadIdx.x == 0) {
        int guard = 0;
        while (__hip_atomic_load(c, __ATOMIC_RELAXED, __HIP_MEMORY_SCOPE_AGENT) < target) {
            __builtin_amdgcn_s_sleep(64);            // ~4096 cy between polls
            if (++guard > (1 << 14)) break;          // ~60 ms bail: wrong beats hang
        }
        (void)__hip_atomic_load(c, __ATOMIC_ACQUIRE, __HIP_MEMORY_SCOPE_AGENT);
    }
    __syncthreads();
}

__device__ __forceinline__ void block_signal(int* c, int amt) {
    __syncthreads();
    if (threadIdx.x == 0)
        __hip_atomic_fetch_add(c, amt, __ATOMIC_RELEASE, __HIP_MEMORY_SCOPE_AGENT);
}

// K1: fused chain through GRU. 533 blocks x 256 threads (~8 waves/CU, all resident).
// blocks 0-15 scores | 16 softmax | 17-20 context | 21-276 combine | 277-532 gru
// gates: cnt0 scores(16) -> cnt1 softmax(1) -> cnt2 ctx(4) -> cnt3 combine(256)
__global__ __launch_bounds__(256) void k_chain(
    const int* __restrict__ token,
    const float* __restrict__ emb,
    const float* __restrict__ hidden,
    const float* __restrict__ enc,
    const float* __restrict__ attn_W,
    const float* __restrict__ attn_b,
    const float* __restrict__ comb_W,
    const float* __restrict__ comb_b,
    const float* __restrict__ W_ih,
    const float* __restrict__ W_hh,
    const float* __restrict__ b_ih,
    const float* __restrict__ b_hh,
    int* __restrict__ cnt,
    float* __restrict__ s_sc,    // [64]
    float* __restrict__ s_w,     // [64]
    float* __restrict__ s_ctx,   // [1024]
    float* __restrict__ s_x,     // [1024]
    float* __restrict__ s_h,     // [1024]
    float* __restrict__ out_h,
    float* __restrict__ out_attn)
{
    __shared__ float wsm[MAXLEN];
    const int t = threadIdx.x;
    const int wid = t >> 6, lane = t & 63;
    const int b = blockIdx.x;

    if (b < 16) {
        // ---- scores: wave per row m ----
        const int m = b * 4 + wid;
        const float4* e4 = (const float4*)(emb + (size_t)token[0] * HIDDEN);
        const float4* h4 = (const float4*)hidden;
        const float4* Wr = (const float4*)(attn_W + (size_t)m * 2 * HIDDEN);
        float acc = 0.f;
        #pragma unroll
        for (int it = 0; it < 8; ++it) {
            int i = lane + it * 64;
            float4 a = Wr[i];
            float4 c = (i < 256) ? e4[i] : h4[i - 256];
            acc += a.x * c.x + a.y * c.y + a.z * c.z + a.w * c.w;
        }
        acc = wave_reduce_sum(acc);
        if (lane == 0) s_sc[m] = acc + attn_b[m];
        block_signal(cnt + 0 * 32, 1);
    } else if (b == 16) {
        // ---- softmax ----
        block_wait(cnt + 0 * 32, 16);
        if (wid == 0) {
            float s = s_sc[lane];
            float mx = s;
            #pragma unroll
            for (int off = 32; off > 0; off >>= 1) mx = fmaxf(mx, __shfl_xor(mx, off, 64));
            float e = expf(s - mx);
            float sum = e;
            #pragma unroll
            for (int off = 32; off > 0; off >>= 1) sum += __shfl_xor(sum, off, 64);
            float wv = e / sum;
            s_w[lane] = wv;
            out_attn[lane] = wv;
        }
        block_signal(cnt + 1 * 32, 1);
    } else if (b < 21) {
        // ---- context: 4 blocks x 256 cols ----
        block_wait(cnt + 1 * 32, 1);
        if (t < MAXLEN) wsm[t] = s_w[t];
        __syncthreads();
        const int h = (b - 17) * 256 + t;
        float acc = 0.f;
        #pragma unroll 8
        for (int m = 0; m < MAXLEN; ++m)
            acc += wsm[m] * enc[(size_t)m * HIDDEN + h];
        s_ctx[h] = acc;
        block_signal(cnt + 2 * 32, 1);
    } else if (b < 277) {
        // ---- combine: wave per row j ----
        block_wait(cnt + 2 * 32, 4);
        const int j = (b - 21) * 4 + wid;
        const float4* e4 = (const float4*)(emb + (size_t)token[0] * HIDDEN);
        const float4* c4 = (const float4*)s_ctx;
        const float4* Wr = (const float4*)(comb_W + (size_t)j * 2 * HIDDEN);
        float acc = 0.f;
        #pragma unroll
        for (int it = 0; it < 8; ++it) {
            int i = lane + it * 64;
            float4 a = Wr[i];
            float4 c = (i < 256) ? e4[i] : c4[i - 256];
            acc += a.x * c.x + a.y * c.y + a.z * c.z + a.w * c.w;
        }
        acc = wave_reduce_sum(acc);
        if (lane == 0) s_x[j] = fmaxf(acc + comb_b[j], 0.f);
        block_signal(cnt + 3 * 32, 1);
    } else {
        // ---- GRU: wave per output element j ----
        block_wait(cnt + 3 * 32, 256);
        const int j = (b - 277) * 4 + wid;
        float d[6];
        const float* rows[6] = {
            W_ih + (size_t)j * HIDDEN,
            W_ih + (size_t)(j + HIDDEN) * HIDDEN,
            W_ih + (size_t)(j + 2 * HIDDEN) * HIDDEN,
            W_hh + (size_t)j * HIDDEN,
            W_hh + (size_t)(j + HIDDEN) * HIDDEN,
            W_hh + (size_t)(j + 2 * HIDDEN) * HIDDEN };
        const float* vecs[2] = { s_x, hidden };
        #pragma unroll
        for (int q = 0; q < 6; ++q) {
            const float4* W4 = (const float4*)rows[q];
            const float4* v4 = (const float4*)vecs[q / 3];
            float acc = 0.f;
            #pragma unroll
            for (int it = 0; it < 4; ++it) {
                int i = lane + it * 64;
                float4 a = W4[i];
                float4 v = v4[i];
                acc += a.x * v.x + a.y * v.y + a.z * v.z + a.w * v.w;
            }
            d[q] = wave_reduce_sum(acc);
        }
        if (lane == 0) {
            float i_r = d[0] + b_ih[j];
            float i_z = d[1] + b_ih[j + HIDDEN];
            float i_n = d[2] + b_ih[j + 2 * HIDDEN];
            float h_r = d[3] + b_hh[j];
            float h_z = d[4] + b_hh[j + HIDDEN];
            float h_n = d[5] + b_hh[j + 2 * HIDDEN];
            float r = 1.f / (1.f + expf(-(i_r + h_r)));
            float z = 1.f / (1.f + expf(-(i_z + h_z)));
            float n = tanhf(i_n + r * h_n);
            float h0v = hidden[j];
            float hn = (1.f - z) * n + z * h0v;
            s_h[j] = hn;
            out_h[j] = hn;
        }
    }
}

// K2: logits, plain kernel (launch boundary = hardware sync, no polling).
// 2 rows per wave, 8 per block.
__global__ __launch_bounds__(256) void k_logits(
    const float* __restrict__ ws_h,
    const float* __restrict__ out_W,
    const float* __restrict__ out_b,
    float* __restrict__ out_logits)
{
    __shared__ float4 hn[HIDDEN / 4];
    const int t = threadIdx.x;
    hn[t] = ((const float4*)ws_h)[t];
    __syncthreads();
    const int wid = t >> 6, lane = t & 63;
    const int v0 = blockIdx.x * 8 + wid * 2;
    const int v1 = v0 + 1;
    if (v0 >= VOCAB) return;
    const float4* W0 = (const float4*)(out_W + (size_t)v0 * HIDDEN);
    const float4* W1 = (const float4*)(out_W + (size_t)v1 * HIDDEN);
    const bool has1 = (v1 < VOCAB);
    float acc0 = 0.f, acc1 = 0.f;
    #pragma unroll
    for (int i = 0; i < 4; ++i) {
        const int idx = lane + i * 64;
        float4 b = hn[idx];
        float4 a0 = W0[idx];
        acc0 += a0.x * b.x + a0.y * b.y + a0.z * b.z + a0.w * b.w;
        if (has1) {
            float4 a1 = W1[idx];
            acc1 += a1.x * b.x + a1.y * b.y + a1.z * b.z + a1.w * b.w;
        }
    }
    acc0 = wave_reduce_sum(acc0);
    acc1 = wave_reduce_sum(acc1);
    if (lane == 0) {
        out_logits[v0] = acc0 + out_b[v0];
        if (has1) out_logits[v1] = acc1 + out_b[v1];
    }
}

extern "C" void kernel_launch(void* const* d_in, const int* in_sizes, int n_in,
                              void* d_out, int out_size, void* d_ws, size_t ws_size,
                              hipStream_t stream) {
    const int*   token  = (const int*)d_in[0];
    const float* hidden = (const float*)d_in[1];
    const float* enc    = (const float*)d_in[2];
    const float* emb    = (const float*)d_in[3];
    const float* attn_W = (const float*)d_in[4];
    const float* attn_b = (const float*)d_in[5];
    const float* comb_W = (const float*)d_in[6];
    const float* comb_b = (const float*)d_in[7];
    const float* W_ih   = (const float*)d_in[8];
    const float* W_hh   = (const float*)d_in[9];
    const float* b_ih   = (const float*)d_in[10];
    const float* b_hh   = (const float*)d_in[11];
    const float* out_W  = (const float*)d_in[12];
    const float* out_b  = (const float*)d_in[13];

    float* out = (float*)d_out;
    float* out_logits = out;                       // [50257]
    float* out_h      = out + VOCAB;               // [1024]
    float* out_attn   = out + VOCAB + HIDDEN;      // [64]

    int* cnt = (int*)d_ws;                         // 4 counters x 128 B = 512 B
    float* wsf = (float*)((char*)d_ws + 512);
    float* s_sc  = wsf;            // 64
    float* s_w   = wsf + 64;       // 64
    float* s_ctx = wsf + 128;      // 1024
    float* s_x   = wsf + 1152;     // 1024
    float* s_h   = wsf + 2176;     // 1024

    hipMemsetAsync(d_ws, 0, 512, stream);
    k_chain<<<533, 256, 0, stream>>>(token, emb, hidden, enc, attn_W, attn_b,
                                     comb_W, comb_b, W_ih, W_hh, b_ih, b_hh,
                                     cnt, s_sc, s_w, s_ctx, s_x, s_h,
                                     out_h, out_attn);
    k_logits<<<(VOCAB + 7) / 8, 256, 0, stream>>>(s_h, out_W, out_b, out_logits);
}

// Round 7
// 53.906 us; speedup vs baseline: 7.5650x; 1.3194x over previous
//
#include <hip/hip_runtime.h>
#include <math.h>

#define HIDDEN 1024
#define VOCAB  50257
#define MAXLEN 64

__device__ __forceinline__ float wave_reduce_sum(float v) {
    #pragma unroll
    for (int off = 32; off > 0; off >>= 1)
        v += __shfl_down(v, off, 64);
    return v;
}

// 64 blocks x 256 threads: scores[m] = dot(concat(emb_row, h0), attn_W[m]) + attn_b[m]
__global__ void k_scores(const int* __restrict__ token,
                         const float* __restrict__ emb,
                         const float* __restrict__ hidden,
                         const float* __restrict__ attn_W,
                         const float* __restrict__ attn_b,
                         float* __restrict__ ws_scores) {
    const int m = blockIdx.x;
    const int t = threadIdx.x;
    const float* erow = emb + (size_t)token[0] * HIDDEN;
    const float4* Wrow = (const float4*)(attn_W + (size_t)m * 2 * HIDDEN);
    float acc = 0.f;
    #pragma unroll
    for (int it = 0; it < 2; ++it) {
        int i = t + it * 256;            // 0..511 float4s
        float4 w4 = Wrow[i];
        int k = i * 4;
        const float* src = (k < HIDDEN) ? (erow + k) : (hidden + k - HIDDEN);
        float4 c4 = *(const float4*)src;
        acc += w4.x * c4.x + w4.y * c4.y + w4.z * c4.z + w4.w * c4.w;
    }
    __shared__ float part[4];
    acc = wave_reduce_sum(acc);
    const int wid = t >> 6, lane = t & 63;
    if (lane == 0) part[wid] = acc;
    __syncthreads();
    if (t == 0)
        ws_scores[m] = part[0] + part[1] + part[2] + part[3] + attn_b[m];
}

// 4 blocks x 256 threads: per-block redundant softmax (1 wave, 64 elems) + context.
__global__ void k_smctx(const float* __restrict__ ws_scores,
                        const float* __restrict__ enc,
                        float* __restrict__ ws_ctx,
                        float* __restrict__ out_attn) {
    __shared__ float wsm[MAXLEN];
    const int t = threadIdx.x;
    const int wid = t >> 6, lane = t & 63;
    if (wid == 0) {
        float s = ws_scores[lane];
        float mx = s;
        #pragma unroll
        for (int off = 32; off > 0; off >>= 1) mx = fmaxf(mx, __shfl_xor(mx, off, 64));
        float e = expf(s - mx);
        float sum = e;
        #pragma unroll
        for (int off = 32; off > 0; off >>= 1) sum += __shfl_xor(sum, off, 64);
        float wv = e / sum;
        wsm[lane] = wv;
        if (blockIdx.x == 0) out_attn[lane] = wv;
    }
    __syncthreads();
    const int h = blockIdx.x * 256 + t;
    float acc = 0.f;
    #pragma unroll 8
    for (int m = 0; m < MAXLEN; ++m)
        acc += wsm[m] * enc[(size_t)m * HIDDEN + h];
    ws_ctx[h] = acc;
}

// 256 blocks x 256 threads (wave per row): x[j] = relu(dot(concat(emb_row, ctx), comb_W[j]) + comb_b[j])
__global__ void k_combine(const int* __restrict__ token,
                          const float* __restrict__ emb,
                          const float* __restrict__ ws_ctx,
                          const float* __restrict__ comb_W,
                          const float* __restrict__ comb_b,
                          float* __restrict__ ws_x) {
    const int wid = threadIdx.x >> 6, lane = threadIdx.x & 63;
    const int j = blockIdx.x * 4 + wid;
    const float* erow = emb + (size_t)token[0] * HIDDEN;
    const float4* Wrow = (const float4*)(comb_W + (size_t)j * 2 * HIDDEN);
    float acc = 0.f;
    #pragma unroll
    for (int it = 0; it < 8; ++it) {
        int i = lane + it * 64;          // 0..511 float4s
        float4 w4 = Wrow[i];
        int k = i * 4;
        const float* src = (k < HIDDEN) ? (erow + k) : (ws_ctx + k - HIDDEN);
        float4 c4 = *(const float4*)src;
        acc += w4.x * c4.x + w4.y * c4.y + w4.z * c4.z + w4.w * c4.w;
    }
    acc = wave_reduce_sum(acc);
    if (lane == 0) ws_x[j] = fmaxf(acc + comb_b[j], 0.f);
}

// 1024 blocks x 384 threads: block j, wave q computes gate-dot q; thread 0 combines.
__global__ __launch_bounds__(384) void k_gru(
    const float* __restrict__ ws_x,
    const float* __restrict__ hidden,
    const float* __restrict__ W_ih,
    const float* __restrict__ W_hh,
    const float* __restrict__ b_ih,
    const float* __restrict__ b_hh,
    float* __restrict__ ws_h,
    float* __restrict__ out_h)
{
    __shared__ float dval[6];
    const int j = blockIdx.x;
    const int q = threadIdx.x >> 6, lane = threadIdx.x & 63;
    const float* row = (q < 3)
        ? (W_ih + (size_t)(j + q * HIDDEN) * HIDDEN)
        : (W_hh + (size_t)(j + (q - 3) * HIDDEN) * HIDDEN);
    const float* vec = (q < 3) ? ws_x : hidden;
    const float4* W4 = (const float4*)row;
    const float4* v4 = (const float4*)vec;
    float acc = 0.f;
    #pragma unroll
    for (int it = 0; it < 4; ++it) {
        int i = lane + it * 64;          // 0..255 float4s
        float4 a = W4[i];
        float4 b = v4[i];
        acc += a.x * b.x + a.y * b.y + a.z * b.z + a.w * b.w;
    }
    acc = wave_reduce_sum(acc);
    if (lane == 0) dval[q] = acc;
    __syncthreads();
    if (threadIdx.x == 0) {
        float i_r = dval[0] + b_ih[j];
        float i_z = dval[1] + b_ih[j + HIDDEN];
        float i_n = dval[2] + b_ih[j + 2 * HIDDEN];
        float h_r = dval[3] + b_hh[j];
        float h_z = dval[4] + b_hh[j + HIDDEN];
        float h_n = dval[5] + b_hh[j + 2 * HIDDEN];
        float r = 1.f / (1.f + expf(-(i_r + h_r)));
        float z = 1.f / (1.f + expf(-(i_z + h_z)));
        float n = tanhf(i_n + r * h_n);
        float h0v = hidden[j];
        float hn = (1.f - z) * n + z * h0v;
        ws_h[j] = hn;
        out_h[j] = hn;
    }
}

// ceil(VOCAB/16) blocks x 256 threads: 4 rows per wave, h kept in REGISTERS
// (no LDS in hot loop), 16 dwordx4 streams in flight per wave.
__global__ __launch_bounds__(256) void k_logits(
    const float* __restrict__ ws_h,
    const float* __restrict__ out_W,
    const float* __restrict__ out_b,
    float* __restrict__ out_logits)
{
    const int t = threadIdx.x;
    const int wid = t >> 6, lane = t & 63;
    const float4* h4 = (const float4*)ws_h;
    const float4 hv0 = h4[lane];
    const float4 hv1 = h4[lane + 64];
    const float4 hv2 = h4[lane + 128];
    const float4 hv3 = h4[lane + 192];

    const int base = blockIdx.x * 16 + wid * 4;
    const float4* W[4];
    #pragma unroll
    for (int r = 0; r < 4; ++r) {
        int v = base + r;
        if (v > VOCAB - 1) v = VOCAB - 1;     // clamp: duplicate read, result discarded
        W[r] = (const float4*)(out_W + (size_t)v * HIDDEN);
    }

    float acc[4];
    #pragma unroll
    for (int r = 0; r < 4; ++r) {
        float4 a0 = W[r][lane];
        float4 a1 = W[r][lane + 64];
        float4 a2 = W[r][lane + 128];
        float4 a3 = W[r][lane + 192];
        float s;
        s  = a0.x * hv0.x + a0.y * hv0.y + a0.z * hv0.z + a0.w * hv0.w;
        s += a1.x * hv1.x + a1.y * hv1.y + a1.z * hv1.z + a1.w * hv1.w;
        s += a2.x * hv2.x + a2.y * hv2.y + a2.z * hv2.z + a2.w * hv2.w;
        s += a3.x * hv3.x + a3.y * hv3.y + a3.z * hv3.z + a3.w * hv3.w;
        acc[r] = s;
    }
    #pragma unroll
    for (int r = 0; r < 4; ++r)
        acc[r] = wave_reduce_sum(acc[r]);
    if (lane == 0) {
        #pragma unroll
        for (int r = 0; r < 4; ++r) {
            const int v = base + r;
            if (v < VOCAB) out_logits[v] = acc[r] + out_b[v];
        }
    }
}

extern "C" void kernel_launch(void* const* d_in, const int* in_sizes, int n_in,
                              void* d_out, int out_size, void* d_ws, size_t ws_size,
                              hipStream_t stream) {
    const int*   token  = (const int*)d_in[0];
    const float* hidden = (const float*)d_in[1];
    const float* enc    = (const float*)d_in[2];
    const float* emb    = (const float*)d_in[3];
    const float* attn_W = (const float*)d_in[4];
    const float* attn_b = (const float*)d_in[5];
    const float* comb_W = (const float*)d_in[6];
    const float* comb_b = (const float*)d_in[7];
    const float* W_ih   = (const float*)d_in[8];
    const float* W_hh   = (const float*)d_in[9];
    const float* b_ih   = (const float*)d_in[10];
    const float* b_hh   = (const float*)d_in[11];
    const float* out_W  = (const float*)d_in[12];
    const float* out_b  = (const float*)d_in[13];

    float* out = (float*)d_out;
    float* out_logits = out;                       // [50257]
    float* out_h      = out + VOCAB;               // [1024]
    float* out_attn   = out + VOCAB + HIDDEN;      // [64]

    float* ws = (float*)d_ws;
    float* ws_scores = ws;            // 64
    float* ws_ctx    = ws + 64;       // 1024
    float* ws_x      = ws + 1088;     // 1024
    float* ws_h      = ws + 2112;     // 1024

    k_scores<<<MAXLEN, 256, 0, stream>>>(token, emb, hidden, attn_W, attn_b, ws_scores);
    k_smctx<<<HIDDEN / 256, 256, 0, stream>>>(ws_scores, enc, ws_ctx, out_attn);
    k_combine<<<HIDDEN / 4, 256, 0, stream>>>(token, emb, ws_ctx, comb_W, comb_b, ws_x);
    k_gru<<<HIDDEN, 384, 0, stream>>>(ws_x, hidden, W_ih, W_hh, b_ih, b_hh, ws_h, out_h);
    k_logits<<<(VOCAB + 15) / 16, 256, 0, stream>>>(ws_h, out_W, out_b, out_logits);
}